// Round 2
// baseline (11568.975 us; speedup 1.0000x reference)
//
#include <hip/hip_runtime.h>

// Problem constants
#define Bn 4096
#define Tn 256
#define Dn 64
#define Hn 256

#define BT  32        // batch rows per workgroup
#define NTH 512       // 8 waves
#define NWG 128       // 4096/32
#define LDH 264       // padded bf16 LDS stride for h tiles (+8 -> balanced banks)
#define LDX 72        // padded bf16 LDS stride for x tile

typedef __attribute__((ext_vector_type(4))) float f32x4;
typedef __attribute__((ext_vector_type(8))) short bf16x8;
typedef __attribute__((ext_vector_type(4))) short s16x4;

#define MFMA16(a,b,c) __builtin_amdgcn_mfma_f32_16x16x32_bf16((a),(b),(c),0,0,0)

// bf16 weight copies in d_ws (element offsets)
#define OFF_WIH1 0
#define OFF_WHH1 49152
#define OFF_WIH2 245760
#define OFF_WHH2 442368
#define OFF_WFC  638976
#define W_TOTAL  655360

__device__ __forceinline__ short f2b(float f){
  union { float fv; unsigned u; } v; v.fv = f;
  unsigned r = v.u + 0x7fffu + ((v.u >> 16) & 1u);   // RNE
  return (short)(r >> 16);
}
__device__ __forceinline__ float sigm(float x){ return 1.f/(1.f+__expf(-x)); }
__device__ __forceinline__ float tanh_s(float x){ float e=__expf(2.f*x); return 1.f - 2.f/(e+1.f); }

__global__ void prep_weights(const float* __restrict__ Wih1, const float* __restrict__ Whh1,
                             const float* __restrict__ Wih2, const float* __restrict__ Whh2,
                             const float* __restrict__ Wfc, short* __restrict__ wsb){
  for (int i = blockIdx.x*blockDim.x + threadIdx.x; i < W_TOTAL; i += gridDim.x*blockDim.x){
    float v;
    if (i < OFF_WHH1)      v = Wih1[i - OFF_WIH1];
    else if (i < OFF_WIH2) v = Whh1[i - OFF_WHH1];
    else if (i < OFF_WHH2) v = Wih2[i - OFF_WIH2];
    else if (i < OFF_WFC)  v = Whh2[i - OFF_WHH2];
    else                   v = Wfc [i - OFF_WFC];
    wsb[i] = f2b(v);
  }
}

__global__ __launch_bounds__(NTH, 2) void gru_fused(
    const float* __restrict__ x,
    const float* __restrict__ h1_in, const float* __restrict__ h2_in,
    const float* __restrict__ b_ih1, const float* __restrict__ b_hh1,
    const float* __restrict__ b_ih2, const float* __restrict__ b_hh2,
    const float* __restrict__ b_fc,
    const short* __restrict__ wsb,
    float* __restrict__ out)
{
  __shared__ short h1b[BT*LDH];
  __shared__ short h2b[BT*LDH];
  __shared__ short xb [BT*LDX];

  const int tid = (int)threadIdx.x;
  const int w   = tid >> 6;     // wave 0..7
  const int l   = tid & 63;
  const int q   = l >> 4;       // 0..3
  const int r16 = l & 15;
  const int b0  = (int)blockIdx.x * BT;

  const short* Wih1 = wsb + OFF_WIH1;
  const short* Whh1 = wsb + OFF_WHH1;
  const short* Wih2 = wsb + OFF_WIH2;
  const short* Whh2 = wsb + OFF_WHH2;
  const short* Wfc  = wsb + OFF_WFC;

  // --- bias preload (per-lane: column is fixed for the whole run) ---
  float bi1[2][3], bh1v[2][3], bi2[2][3], bh2v[2][3];
#pragma unroll
  for (int c=0;c<2;++c)
#pragma unroll
    for (int g=0;g<3;++g){
      const int col = g*Hn + (2*w+c)*16 + r16;
      bi1 [c][g] = b_ih1[col];  bh1v[c][g] = b_hh1[col];
      bi2 [c][g] = b_ih2[col];  bh2v[c][g] = b_hh2[col];
    }
  const float bfc = b_fc[(w&3)*16 + r16];

  // --- h state init: fp32 in registers (D-frag layout), bf16 copy in LDS ---
  float h1s[2][2][4], h2s[2][2][4];   // [row-tile][col-sub][j]
#pragma unroll
  for (int rt=0;rt<2;++rt)
#pragma unroll
    for (int c=0;c<2;++c)
#pragma unroll
      for (int j=0;j<4;++j){
        const int row = rt*16 + q*4 + j;
        const int col = (2*w+c)*16 + r16;
        const float v1 = h1_in[(size_t)(b0+row)*Hn + col];
        const float v2 = h2_in[(size_t)(b0+row)*Hn + col];
        h1s[rt][c][j] = v1;  h2s[rt][c][j] = v2;
        h1b[row*LDH + col] = f2b(v1);
        h2b[row*LDH + col] = f2b(v2);
      }
  __syncthreads();

  const int xr = tid >> 4;        // 0..31
  const int xd = (tid & 15) * 4;  // 0..60
  const f32x4 z4 = {0.f,0.f,0.f,0.f};

  for (int t=0; t<Tn; ++t){
    // ---- stage x_t -> LDS bf16 ----
    {
      const float4 xv = *(const float4*)(x + ((size_t)(b0+xr)*Tn + t)*Dn + xd);
      s16x4 pk; pk.x=f2b(xv.x); pk.y=f2b(xv.y); pk.z=f2b(xv.z); pk.w=f2b(xv.w);
      *(s16x4*)&xb[xr*LDX + xd] = pk;
    }
    __syncthreads();

    // ---- layer 1: gi1 = x@Wih1^T, gh1 = h1@Whh1^T ----
    f32x4 gi[2][2][3], gh[2][2][3];
#pragma unroll
    for (int rt=0;rt<2;++rt)
#pragma unroll
      for (int c=0;c<2;++c)
#pragma unroll
        for (int g=0;g<3;++g){ gi[rt][c][g]=z4; gh[rt][c][g]=z4; }

#pragma unroll
    for (int k=0;k<2;++k){             // K=64
      const bf16x8 ax0 = *(const bf16x8*)&xb[(r16   )*LDX + k*32 + q*8];
      const bf16x8 ax1 = *(const bf16x8*)&xb[(16+r16)*LDX + k*32 + q*8];
#pragma unroll
      for (int c=0;c<2;++c)
#pragma unroll
        for (int g=0;g<3;++g){
          const int col = g*Hn + (2*w+c)*16;
          const bf16x8 bx = *(const bf16x8*)&Wih1[(size_t)(col + r16)*Dn + k*32 + q*8];
          gi[0][c][g] = MFMA16(ax0, bx, gi[0][c][g]);
          gi[1][c][g] = MFMA16(ax1, bx, gi[1][c][g]);
        }
    }
    for (int k=0;k<8;++k){             // K=256
      const bf16x8 a0 = *(const bf16x8*)&h1b[(r16   )*LDH + k*32 + q*8];
      const bf16x8 a1 = *(const bf16x8*)&h1b[(16+r16)*LDH + k*32 + q*8];
#pragma unroll
      for (int c=0;c<2;++c)
#pragma unroll
        for (int g=0;g<3;++g){
          const int col = g*Hn + (2*w+c)*16;
          const bf16x8 bb = *(const bf16x8*)&Whh1[(size_t)(col + r16)*Hn + k*32 + q*8];
          gh[0][c][g] = MFMA16(a0, bb, gh[0][c][g]);
          gh[1][c][g] = MFMA16(a1, bb, gh[1][c][g]);
        }
    }
    __syncthreads();   // all h1b/xb reads complete

    // ---- gates layer 1 (fp32), update h1 ----
#pragma unroll
    for (int rt=0;rt<2;++rt)
#pragma unroll
      for (int c=0;c<2;++c){
        const int colb = (2*w+c)*16 + r16;
#pragma unroll
        for (int j=0;j<4;++j){
          const float rr = sigm(gi[rt][c][0][j]+bi1[c][0] + gh[rt][c][0][j]+bh1v[c][0]);
          const float zz = sigm(gi[rt][c][1][j]+bi1[c][1] + gh[rt][c][1][j]+bh1v[c][1]);
          const float nn = tanh_s(gi[rt][c][2][j]+bi1[c][2] + rr*(gh[rt][c][2][j]+bh1v[c][2]));
          const float hv = (1.f-zz)*nn + zz*h1s[rt][c][j];
          h1s[rt][c][j] = hv;
          h1b[(rt*16 + q*4 + j)*LDH + colb] = f2b(hv);
        }
      }
    __syncthreads();   // new h1b ready

    // ---- layer 2: gi2 = h1@Wih2^T, gh2 = h2@Whh2^T ----
#pragma unroll
    for (int rt=0;rt<2;++rt)
#pragma unroll
      for (int c=0;c<2;++c)
#pragma unroll
        for (int g=0;g<3;++g){ gi[rt][c][g]=z4; gh[rt][c][g]=z4; }

    for (int k=0;k<8;++k){
      const bf16x8 p0 = *(const bf16x8*)&h1b[(r16   )*LDH + k*32 + q*8];
      const bf16x8 p1 = *(const bf16x8*)&h1b[(16+r16)*LDH + k*32 + q*8];
      const bf16x8 s0 = *(const bf16x8*)&h2b[(r16   )*LDH + k*32 + q*8];
      const bf16x8 s1 = *(const bf16x8*)&h2b[(16+r16)*LDH + k*32 + q*8];
#pragma unroll
      for (int c=0;c<2;++c)
#pragma unroll
        for (int g=0;g<3;++g){
          const int col = g*Hn + (2*w+c)*16;
          const bf16x8 wi = *(const bf16x8*)&Wih2[(size_t)(col + r16)*Hn + k*32 + q*8];
          const bf16x8 wh = *(const bf16x8*)&Whh2[(size_t)(col + r16)*Hn + k*32 + q*8];
          gi[0][c][g] = MFMA16(p0, wi, gi[0][c][g]);
          gi[1][c][g] = MFMA16(p1, wi, gi[1][c][g]);
          gh[0][c][g] = MFMA16(s0, wh, gh[0][c][g]);
          gh[1][c][g] = MFMA16(s1, wh, gh[1][c][g]);
        }
    }
    __syncthreads();   // all h2b (old) reads complete

    // ---- gates layer 2 (fp32), update h2 ----
#pragma unroll
    for (int rt=0;rt<2;++rt)
#pragma unroll
      for (int c=0;c<2;++c){
        const int colb = (2*w+c)*16 + r16;
#pragma unroll
        for (int j=0;j<4;++j){
          const float rr = sigm(gi[rt][c][0][j]+bi2[c][0] + gh[rt][c][0][j]+bh2v[c][0]);
          const float zz = sigm(gi[rt][c][1][j]+bi2[c][1] + gh[rt][c][1][j]+bh2v[c][1]);
          const float nn = tanh_s(gi[rt][c][2][j]+bi2[c][2] + rr*(gh[rt][c][2][j]+bh2v[c][2]));
          const float hv = (1.f-zz)*nn + zz*h2s[rt][c][j];
          h2s[rt][c][j] = hv;
          h2b[(rt*16 + q*4 + j)*LDH + colb] = f2b(hv);
        }
      }
    __syncthreads();   // new h2b ready

    // ---- fc head: y_t = h2@Wfc^T + b_fc ----
    {
      const int rt = w >> 2, ct = w & 3;   // 8 waves cover 2x4 16x16 tiles of [32x64]
      f32x4 acc = z4;
      for (int k=0;k<8;++k){
        const bf16x8 a = *(const bf16x8*)&h2b[(rt*16 + r16)*LDH + k*32 + q*8];
        const bf16x8 b = *(const bf16x8*)&Wfc[(size_t)(ct*16 + r16)*Hn + k*32 + q*8];
        acc = MFMA16(a, b, acc);
      }
#pragma unroll
      for (int j=0;j<4;++j){
        out[((size_t)(b0 + rt*16 + q*4 + j)*Tn + t)*Dn + ct*16 + r16] = acc[j] + bfc;
      }
    }
  } // t loop

  // ---- final states ----
  const size_t offH1 = (size_t)Bn*Tn*Dn;
  const size_t offH2 = offH1 + (size_t)Bn*Hn;
#pragma unroll
  for (int rt=0;rt<2;++rt)
#pragma unroll
    for (int c=0;c<2;++c)
#pragma unroll
      for (int j=0;j<4;++j){
        const int row = b0 + rt*16 + q*4 + j;
        const int col = (2*w+c)*16 + r16;
        out[offH1 + (size_t)row*Hn + col] = h1s[rt][c][j];
        out[offH2 + (size_t)row*Hn + col] = h2s[rt][c][j];
      }
}

extern "C" void kernel_launch(void* const* d_in, const int* in_sizes, int n_in,
                              void* d_out, int out_size, void* d_ws, size_t ws_size,
                              hipStream_t stream) {
  const float* x    = (const float*)d_in[0];
  const float* h1i  = (const float*)d_in[1];
  const float* h2i  = (const float*)d_in[2];
  const float* Wih1 = (const float*)d_in[3];
  const float* Whh1 = (const float*)d_in[4];
  const float* bih1 = (const float*)d_in[5];
  const float* bhh1 = (const float*)d_in[6];
  const float* Wih2 = (const float*)d_in[7];
  const float* Whh2 = (const float*)d_in[8];
  const float* bih2 = (const float*)d_in[9];
  const float* bhh2 = (const float*)d_in[10];
  const float* Wfc  = (const float*)d_in[11];
  const float* bfc  = (const float*)d_in[12];
  short* wsb = (short*)d_ws;
  float* out = (float*)d_out;

  hipLaunchKernelGGL(prep_weights, dim3(512), dim3(256), 0, stream,
                     Wih1, Whh1, Wih2, Whh2, Wfc, wsb);
  hipLaunchKernelGGL(gru_fused, dim3(NWG), dim3(NTH), 0, stream,
                     x, h1i, h2i, bih1, bhh1, bih2, bhh2, bfc, wsb, out);
}